// Round 3
// baseline (2254.794 us; speedup 1.0000x reference)
//
#include <hip/hip_runtime.h>

#define NPTS   100000
#define BIGF   3.4e38f
#define NS_ITERS 26
#define NB     256
#define NCAND  3910          // 782 chunks * 5

// scal[] slots
#define SC_LM   0
#define SC_TRCX 1
#define SC_TRCT 2
#define SC_FROB 3
#define SC_KNN  4
#define SC_REG  5
#define SC_LD   6

// ---- ws layout (float offsets) ----
#define O_MUSUM 0            // 256
#define O_SCAL  256          // 16
#define O_FLAGS 512          // 256 flags * 32 ints = 8192
#define O_COVXA 8704         // 65536 (atomic accumulator)
#define O_COVX  74240        // 65536 (finalized)
#define O_TM    139776       // 65536
#define O_COV   205312       // 65536
#define O_G     270848       // 65536
#define O_Y0    336384
#define O_Y0T   401920
#define O_Z0    467456
#define O_Z0T   532992
#define O_Y1    598528
#define O_Y1T   664064
#define O_Z1    729600
#define O_Z1T   795136
#define O_P     860672
#define O_PT    926208       // ends 991744
#define O_MUT   991744       // 256
#define O_XSQ   992000       // 100000
#define O_POSTW 1092000      // 4096
#define O_POSTI 1096096      // 4096 ints
#define O_CAND  1100192      // 8192 ints
#define O_TB    1108384      // 32768 floats = 65536 ushorts
#define O_XB    1141152      // 100000*256 ushorts = 12800000 floats
#define O_CK    13941152     // 256*3910 = 1000960
#define O_CI    14942112     // 1000960 ints -> ends 15943072 floats (63.77 MB)

typedef __bf16 bfx8 __attribute__((ext_vector_type(8)));
typedef float  fx4  __attribute__((ext_vector_type(4)));

__device__ __forceinline__ ushort f2bf(float f) {
    uint u = __float_as_uint(f);
    u = (u + 0x7FFFu + ((u >> 16) & 1u)) >> 16;   // RNE
    return (ushort)u;
}

// ---------------- zero init (mu_sum, scal, flags, covX acc) ----------------
__global__ __launch_bounds__(256) void zero_kernel(float* ws) {
    int idx = blockIdx.x * 256 + threadIdx.x;
    if (idx < 74240) ws[idx] = 0.0f;
}

// ---------------- reg: sum(W^2) ----------------
__global__ __launch_bounds__(256) void reg_kernel(const float* __restrict__ W, float* __restrict__ scal) {
    __shared__ float red[256];
    int t = threadIdx.x;
    float s = 0.f;
    int base = blockIdx.x * 1024;
    for (int m = 0; m < 4; ++m) { float w = W[base + m * 256 + t]; s += w * w; }
    red[t] = s;
    __syncthreads();
    for (int s2 = 128; s2 > 0; s2 >>= 1) { if (t < s2) red[t] += red[t + s2]; __syncthreads(); }
    if (t == 0) atomicAdd(&scal[SC_REG], red[0]);
}

// ---------------- X stats + bf16 convert ----------------
__global__ __launch_bounds__(256) void statsconv(const float* __restrict__ X,
                                                 float* __restrict__ xsq,
                                                 float* __restrict__ mu_sum,
                                                 ushort* __restrict__ Xb) {
    int w    = threadIdx.x >> 6;
    int lane = threadIdx.x & 63;
    int rbase = blockIdx.x * 1024;
    float cs0 = 0.f, cs1 = 0.f, cs2 = 0.f, cs3 = 0.f;
    for (int m = 0; m < 256; ++m) {
        int r = rbase + w + 4 * m;
        if (r < NPTS) {
            float4 v = *(const float4*)&X[(size_t)r * 256 + 4 * lane];
            cs0 += v.x; cs1 += v.y; cs2 += v.z; cs3 += v.w;
            ushort4 bq;
            bq.x = f2bf(v.x); bq.y = f2bf(v.y); bq.z = f2bf(v.z); bq.w = f2bf(v.w);
            *(ushort4*)&Xb[(size_t)r * 256 + 4 * lane] = bq;
            float ss = v.x * v.x + v.y * v.y + v.z * v.z + v.w * v.w;
            for (int off = 32; off; off >>= 1) ss += __shfl_down(ss, off);
            if (lane == 0) xsq[r] = ss;
        }
    }
    atomicAdd(&mu_sum[4 * lane + 0], cs0);
    atomicAdd(&mu_sum[4 * lane + 1], cs1);
    atomicAdd(&mu_sum[4 * lane + 2], cs2);
    atomicAdd(&mu_sum[4 * lane + 3], cs3);
}

// ---------------- covX accumulate via bf16 MFMA (3 symmetric combos x 42 k-slices) ----------------
__global__ __launch_bounds__(256, 2) void covx_mfma(const ushort* __restrict__ Xb,
                                                    float* __restrict__ acc_out) {
    __shared__ ushort XT[2][128][40];
    int t = threadIdx.x;
    int combo = blockIdx.x % 3;
    int i0 = (combo == 2) ? 128 : 0;
    int j0 = (combo == 0) ? 0 : 128;
    int ks = (blockIdx.x / 3) * 2400;
    int wv = t >> 6, lane = t & 63;
    int quad = lane >> 4, m16 = lane & 15;
    fx4 acc[16];
#pragma unroll
    for (int i = 0; i < 16; ++i) acc[i] = (fx4){0.f, 0.f, 0.f, 0.f};

    for (int kb = 0; kb < 2400; kb += 32) {
        __syncthreads();
#pragma unroll
        for (int s = 0; s < 4; ++s) {
            int id = t + 256 * s;
            int kk = id & 31;
            int g  = (id >> 5) & 15;
            int h  = id >> 9;
            int kg = ks + kb + kk;
            int dbase = (h ? j0 : i0) + g * 8;
            union { uint4 u; ushort sh[8]; } cv;
            if (kg < NPTS) cv.u = *(const uint4*)&Xb[(size_t)kg * 256 + dbase];
            else           cv.u = (uint4){0, 0, 0, 0};
#pragma unroll
            for (int jj = 0; jj < 8; ++jj) XT[h][g * 8 + jj][kk] = cv.sh[jj];
        }
        __syncthreads();
        bfx8 afr[2], bfr[8];
#pragma unroll
        for (int a = 0; a < 2; ++a)
            afr[a] = *(const bfx8*)&XT[0][(wv * 2 + a) * 16 + m16][quad * 8];
#pragma unroll
        for (int bj = 0; bj < 8; ++bj)
            bfr[bj] = *(const bfx8*)&XT[1][bj * 16 + m16][quad * 8];
#pragma unroll
        for (int a = 0; a < 2; ++a)
#pragma unroll
            for (int bj = 0; bj < 8; ++bj)
                acc[a * 8 + bj] = __builtin_amdgcn_mfma_f32_16x16x32_bf16(afr[a], bfr[bj], acc[a * 8 + bj], 0, 0, 0);
    }
#pragma unroll
    for (int a = 0; a < 2; ++a)
#pragma unroll
        for (int bj = 0; bj < 8; ++bj)
#pragma unroll
            for (int r = 0; r < 4; ++r) {
                int i = i0 + (wv * 2 + a) * 16 + quad * 4 + r;
                int j = j0 + bj * 16 + m16;
                atomicAdd(&acc_out[i * 256 + j], acc[a * 8 + bj][r]);
            }
}

// ---------------- flag-array grid barrier ----------------
__device__ __forceinline__ void gbar(int* flags, int ph, int b, int t) {
    __syncthreads();
    if (t == 0) {
        __threadfence();
        __hip_atomic_store(&flags[b * 32], ph, __ATOMIC_RELEASE, __HIP_MEMORY_SCOPE_AGENT);
    }
    if (t < 64) {
        long spins = 0;
        for (;;) {
            int v0 = __hip_atomic_load(&flags[t * 32],         __ATOMIC_RELAXED, __HIP_MEMORY_SCOPE_AGENT);
            int v1 = __hip_atomic_load(&flags[(t + 64) * 32],  __ATOMIC_RELAXED, __HIP_MEMORY_SCOPE_AGENT);
            int v2 = __hip_atomic_load(&flags[(t + 128) * 32], __ATOMIC_RELAXED, __HIP_MEMORY_SCOPE_AGENT);
            int v3 = __hip_atomic_load(&flags[(t + 192) * 32], __ATOMIC_RELAXED, __HIP_MEMORY_SCOPE_AGENT);
            bool ok = (v0 >= ph) && (v1 >= ph) && (v2 >= ph) && (v3 >= ph);
            if (__all(ok)) break;
            __builtin_amdgcn_s_sleep(1);
            if (++spins > (1L << 18)) break;   // failsafe: fail loud, not hung
        }
        if (t == 0) __threadfence();
    }
    __syncthreads();
}

// ---------------- 32x32-tile mm, K=256, A given as its transpose (row-major) ----------------
// C[i0+di][j0+dj] = sum_k AT[k][i0+di] * B[k][j0+dj]
__device__ __forceinline__ void mmv2(const float* __restrict__ AT, const float* __restrict__ B,
                                     int i0, int j0, float (*Ast)[36], float (*Bst)[36],
                                     float acc[2][2], int t) {
    {
        const float4* ar = (const float4*)&AT[t * 256 + i0];
        const float4* br = (const float4*)&B[t * 256 + j0];
        float4 av[8], bv[8];
#pragma unroll
        for (int m = 0; m < 8; ++m) { av[m] = ar[m]; bv[m] = br[m]; }
#pragma unroll
        for (int m = 0; m < 8; ++m) {
            *(float4*)&Ast[t][4 * m] = av[m];
            *(float4*)&Bst[t][4 * m] = bv[m];
        }
    }
    __syncthreads();
    int tx = t & 15, ty = t >> 4;
    float a00 = 0.f, a01 = 0.f, a10 = 0.f, a11 = 0.f;
#pragma unroll 8
    for (int kk = 0; kk < 256; ++kk) {
        float2 a = *(const float2*)&Ast[kk][2 * tx];
        float2 bb = *(const float2*)&Bst[kk][2 * ty];
        a00 += a.x * bb.x; a01 += a.x * bb.y;
        a10 += a.y * bb.x; a11 += a.y * bb.y;
    }
    acc[0][0] = a00; acc[0][1] = a01; acc[1][0] = a10; acc[1][1] = a11;
}

// ---------------- persistent chain: covxfin + T + stats + cov + G + NS + findist ----------------
__global__ __launch_bounds__(256, 1) void persist(const float* __restrict__ qb,
                                                  const float* __restrict__ W,
                                                  float* __restrict__ ws) {
    __shared__ float Ast[256][36];
    __shared__ float Bst[256][36];
    __shared__ float red[256];
    int b = blockIdx.x, t = threadIdx.x;
    int* flags = (int*)(ws + O_FLAGS);
    float* scal = ws + O_SCAL;
    float* acc_cx = ws + O_COVXA;
    float* covX = ws + O_COVX;
    float* Tm = ws + O_TM;
    float* cov = ws + O_COV;
    float* G = ws + O_G;
    float* muT = ws + O_MUT;
    const float* mu_sum = ws + O_MUSUM;
    ushort* TbO = (ushort*)(ws + O_TB);
    const float invN = 1.0f / (float)NPTS;

    int tx = t & 15, ty = t >> 4;
    int i0 = ((b & 63) >> 3) * 32, j0 = ((b & 63) & 7) * 32;   // tile coords for b<64 (and b-64 reuse)
    float acc[2][2];

    // ---- ph0: covX finalize (row b) + T = qb@W (blocks 0..63) ----
    {
        int r = b, c = t;
        float raw = (r >= 128 && c < 128) ? acc_cx[c * 256 + r] : acc_cx[r * 256 + c];
        float v = raw * invN - (mu_sum[r] * invN) * (mu_sum[c] * invN) + ((r == c) ? 1e-4f : 0.f);
        covX[r * 256 + c] = v;
        if (c == r) atomicAdd(&scal[SC_TRCX], v);
    }
    if (b < 64) {
        {   // stage qb^T (scalar transpose writes, 2-way-free banks)
            int r = t & 31, kg = t >> 5;
            const float4* src = (const float4*)&qb[(i0 + r) * 256 + kg * 32];
            float4 v[8];
#pragma unroll
            for (int m = 0; m < 8; ++m) v[m] = src[m];
#pragma unroll
            for (int m = 0; m < 8; ++m) {
                Ast[kg * 32 + 4 * m + 0][r] = v[m].x;
                Ast[kg * 32 + 4 * m + 1][r] = v[m].y;
                Ast[kg * 32 + 4 * m + 2][r] = v[m].z;
                Ast[kg * 32 + 4 * m + 3][r] = v[m].w;
            }
        }
        {   // stage W rows
            const float4* br = (const float4*)&W[t * 256 + j0];
            float4 v[8];
#pragma unroll
            for (int m = 0; m < 8; ++m) v[m] = br[m];
#pragma unroll
            for (int m = 0; m < 8; ++m) *(float4*)&Bst[t][4 * m] = v[m];
        }
        __syncthreads();
        float a00 = 0.f, a01 = 0.f, a10 = 0.f, a11 = 0.f;
#pragma unroll 8
        for (int kk = 0; kk < 256; ++kk) {
            float2 a = *(const float2*)&Ast[kk][2 * tx];
            float2 bb = *(const float2*)&Bst[kk][2 * ty];
            a00 += a.x * bb.x; a01 += a.x * bb.y;
            a10 += a.y * bb.x; a11 += a.y * bb.y;
        }
        acc[0][0] = a00; acc[0][1] = a01; acc[1][0] = a10; acc[1][1] = a11;
#pragma unroll
        for (int ii = 0; ii < 2; ++ii)
#pragma unroll
            for (int jj = 0; jj < 2; ++jj) {
                int i = i0 + 2 * tx + ii, j = j0 + 2 * ty + jj;
                float vv = acc[ii][jj];
                Tm[i * 256 + j] = vv;
                TbO[i * 256 + j] = f2bf(vv);
            }
    }
    gbar(flags, 1, b, t);

    // ---- ph1: muT (col b) + loss_mean ----
    {
        red[t] = Tm[t * 256 + b];
        __syncthreads();
        for (int s2 = 128; s2 > 0; s2 >>= 1) { if (t < s2) red[t] += red[t + s2]; __syncthreads(); }
        if (t == 0) {
            float mt = red[0] * (1.0f / 256.0f);
            muT[b] = mt;
            float dm = mt - mu_sum[b] * invN;
            atomicAdd(&scal[SC_LM], dm * dm);
        }
    }
    gbar(flags, 2, b, t);

    // ---- ph2: cov = T^T T /256 - muT muT^T + dI (AT-source = Tm itself) ----
    if (b < 64) {
        mmv2(Tm, Tm, i0, j0, Ast, Bst, acc, t);
#pragma unroll
        for (int ii = 0; ii < 2; ++ii)
#pragma unroll
            for (int jj = 0; jj < 2; ++jj) {
                int i = i0 + 2 * tx + ii, j = j0 + 2 * ty + jj;
                float v = acc[ii][jj] * (1.0f / 256.0f) - muT[i] * muT[j] + ((i == j) ? 1e-4f : 0.f);
                cov[i * 256 + j] = v;
                if (i == j) atomicAdd(&scal[SC_TRCT], v);
            }
    }
    gbar(flags, 3, b, t);

    // ---- ph3: G = cov @ covX (cov symmetric -> AT-source = cov) + frob ----
    if (b < 64) {
        mmv2(cov, covX, i0, j0, Ast, Bst, acc, t);
        float fr = 0.f;
#pragma unroll
        for (int ii = 0; ii < 2; ++ii)
#pragma unroll
            for (int jj = 0; jj < 2; ++jj) {
                int i = i0 + 2 * tx + ii, j = j0 + 2 * ty + jj;
                G[i * 256 + j] = acc[ii][jj];
                fr += acc[ii][jj] * acc[ii][jj];
            }
        __syncthreads();
        red[t] = fr;
        __syncthreads();
        for (int s2 = 128; s2 > 0; s2 >>= 1) { if (t < s2) red[t] += red[t + s2]; __syncthreads(); }
        if (t == 0) atomicAdd(&scal[SC_FROB], red[0]);
    }
    gbar(flags, 4, b, t);

    // ---- ph4: Y0 = G/||G||_F (+transpose), Z0 = I (+transpose); row b ----
    {
        float invs = rsqrtf(scal[SC_FROB]);
        float* Y0 = ws + O_Y0; float* Y0T = ws + O_Y0T;
        float* Z0 = ws + O_Z0; float* Z0T = ws + O_Z0T;
        int r = b, c = t;
        float y = G[r * 256 + c] * invs;
        Y0[r * 256 + c] = y;  Y0T[c * 256 + r] = y;
        float z = (r == c) ? 1.0f : 0.0f;
        Z0[r * 256 + c] = z;  Z0T[c * 256 + r] = z;
    }
    gbar(flags, 5, b, t);

    // ---- NS loop ----
    float* Yc = ws + O_Y0; float* YcT = ws + O_Y0T;
    float* Zc = ws + O_Z0; float* ZcT = ws + O_Z0T;
    float* Yn = ws + O_Y1; float* YnT = ws + O_Y1T;
    float* Zn = ws + O_Z1; float* ZnT = ws + O_Z1T;
    float* Pm = ws + O_P;  float* PmT = ws + O_PT;
    int ph = 5;
    for (int it = 0; it < NS_ITERS; ++it) {
        if (b < 64) {
            mmv2(ZcT, Yc, i0, j0, Ast, Bst, acc, t);
#pragma unroll
            for (int ii = 0; ii < 2; ++ii)
#pragma unroll
                for (int jj = 0; jj < 2; ++jj) {
                    int i = i0 + 2 * tx + ii, j = j0 + 2 * ty + jj;
                    float v = ((i == j) ? 1.5f : 0.f) - 0.5f * acc[ii][jj];
                    Pm[i * 256 + j] = v;  PmT[j * 256 + i] = v;
                }
        }
        ++ph; gbar(flags, ph, b, t);
        if (b < 64) {
            mmv2(YcT, Pm, i0, j0, Ast, Bst, acc, t);
#pragma unroll
            for (int ii = 0; ii < 2; ++ii)
#pragma unroll
                for (int jj = 0; jj < 2; ++jj) {
                    int i = i0 + 2 * tx + ii, j = j0 + 2 * ty + jj;
                    float v = acc[ii][jj];
                    Yn[i * 256 + j] = v;  YnT[j * 256 + i] = v;
                }
        } else if (b < 128) {
            mmv2(PmT, Zc, i0, j0, Ast, Bst, acc, t);
#pragma unroll
            for (int ii = 0; ii < 2; ++ii)
#pragma unroll
                for (int jj = 0; jj < 2; ++jj) {
                    int i = i0 + 2 * tx + ii, j = j0 + 2 * ty + jj;
                    float v = acc[ii][jj];
                    Zn[i * 256 + j] = v;  ZnT[j * 256 + i] = v;
                }
        }
        ++ph; gbar(flags, ph, b, t);
        float* tp;
        tp = Yc; Yc = Yn; Yn = tp;   tp = YcT; YcT = YnT; YnT = tp;
        tp = Zc; Zc = Zn; Zn = tp;   tp = ZcT; ZcT = ZnT; ZnT = tp;
    }
    // ---- findist ----
    if (b == 0) {
        red[t] = Yc[t * 257];
        __syncthreads();
        for (int s2 = 128; s2 > 0; s2 >>= 1) { if (t < s2) red[t] += red[t + s2]; __syncthreads(); }
        if (t == 0) {
            float frobsq = scal[SC_FROB];
            float tr_sqrt = sqrtf(sqrtf(frobsq)) * red[0];
            float lc = scal[SC_TRCX] + scal[SC_TRCT] - 2.0f * tr_sqrt;
            scal[SC_LD] = fmaxf(0.0f, scal[SC_LM] + lc);
        }
    }
}

// ---------------- KNN: 128q x 128p per block, Tb-half LDS-resident ----------------
__global__ __launch_bounds__(256, 1) void knn_mfma(const ushort* __restrict__ Xb,
                                                   const ushort* __restrict__ Tb,
                                                   const float* __restrict__ xsq,
                                                   float* __restrict__ ck, int* __restrict__ ci) {
    __shared__ uint4 TbU[128 * 33];      // 67.6 KB; reused as keys after MFMA
    __shared__ uint4 XtU[2][4 * 130];    // 2 x 8.3 KB
    __shared__ float t5k[5][128];
    __shared__ int   t5i[5][128];
    __shared__ float xss[128];
    int t = threadIdx.x;
    int w = t >> 6, lane = t & 63;
    int quad = lane >> 4, m16 = lane & 15;
    int p0 = blockIdx.x * 128, q0 = blockIdx.y * 128;

    {   // preload Tb half [q][k] padded to 33 uint4/row
        int q = t >> 1, ub = (t & 1) * 16;
        const uint4* src = (const uint4*)&Tb[(q0 + q) * 256];
#pragma unroll
        for (int m = 0; m < 16; ++m) TbU[q * 33 + ub + m] = src[ub + m];
    }
    if (t < 128) xss[t] = (p0 + t < NPTS) ? xsq[p0 + t] : BIGF;
    {   // stage XT buf 0 (kb=0)
#pragma unroll
        for (int s = 0; s < 2; ++s) {
            int id = t + 256 * s, qd = id & 3, p = id >> 2;
            uint4 v = (uint4){0, 0, 0, 0};
            if (p0 + p < NPTS) v = *(const uint4*)&Xb[(size_t)(p0 + p) * 256 + qd * 8];
            XtU[0][qd * 130 + p] = v;
        }
    }
    __syncthreads();

    fx4 acc[2][8];
#pragma unroll
    for (int a = 0; a < 2; ++a)
#pragma unroll
        for (int pf = 0; pf < 8; ++pf) acc[a][pf] = (fx4){0.f, 0.f, 0.f, 0.f};

    int cur = 0;
    for (int step = 0; step < 8; ++step) {
        int kb = step * 32;
        uint4 pv[2];
        bool havn = (step < 7);
        if (havn) {
#pragma unroll
            for (int s = 0; s < 2; ++s) {
                int id = t + 256 * s, qd = id & 3, p = id >> 2;
                pv[s] = (uint4){0, 0, 0, 0};
                if (p0 + p < NPTS) pv[s] = *(const uint4*)&Xb[(size_t)(p0 + p) * 256 + kb + 32 + qd * 8];
            }
        }
        bfx8 af[2];
#pragma unroll
        for (int qf = 0; qf < 2; ++qf)
            af[qf] = *(const bfx8*)&TbU[(32 * w + qf * 16 + m16) * 33 + (kb >> 3) + quad];
#pragma unroll
        for (int pf = 0; pf < 8; ++pf) {
            bfx8 bf_ = *(const bfx8*)&XtU[cur][quad * 130 + pf * 16 + m16];
#pragma unroll
            for (int qf = 0; qf < 2; ++qf)
                acc[qf][pf] = __builtin_amdgcn_mfma_f32_16x16x32_bf16(af[qf], bf_, acc[qf][pf], 0, 0, 0);
        }
        __syncthreads();
        if (havn) {
#pragma unroll
            for (int s = 0; s < 2; ++s) {
                int id = t + 256 * s, qd = id & 3, p = id >> 2;
                XtU[cur ^ 1][qd * 130 + p] = pv[s];
            }
            cur ^= 1;
            __syncthreads();
        }
    }
    __syncthreads();
    // dump keys (overlay TbU region), pitch 129
    float* kt = (float*)TbU;
#pragma unroll
    for (int qf = 0; qf < 2; ++qf)
#pragma unroll
        for (int pf = 0; pf < 8; ++pf)
#pragma unroll
            for (int r = 0; r < 4; ++r) {
                int ql = 32 * w + qf * 16 + quad * 4 + r;
                int p = pf * 16 + m16;
                kt[ql * 129 + p] = xss[p] - 2.0f * acc[qf][pf][r];
            }
    __syncthreads();
    // top-5 per query over 128 points
    if (t < 128) {
#pragma unroll
        for (int s = 0; s < 5; ++s) { t5k[s][t] = BIGF; t5i[s][t] = 0x7fffffff; }
        float worst = BIGF; int wslot = 0;
        for (int c = 0; c < 128; ++c) {
            float key = kt[t * 129 + c];
            if (key < worst) {
                t5k[wslot][t] = key; t5i[wslot][t] = p0 + c;
                worst = t5k[0][t]; wslot = 0;
#pragma unroll
                for (int s = 1; s < 5; ++s)
                    if (t5k[s][t] > worst) { worst = t5k[s][t]; wslot = s; }
            }
        }
        int base = (q0 + t) * NCAND + blockIdx.x * 5;
#pragma unroll
        for (int s = 0; s < 5; ++s) { ck[base + s] = t5k[s][t]; ci[base + s] = t5i[s][t]; }
    }
}

// ---------------- global merge: top-32 per query (one wave per query, 4/block) ----------------
__global__ __launch_bounds__(256) void merge_kernel(const float* __restrict__ ck,
                                                    const int* __restrict__ ci,
                                                    int* __restrict__ cand32) {
    __shared__ float sk[8][256];
    __shared__ int   si[8][256];
    int t = threadIdx.x, lane = t & 63, w = t >> 6;
    int q = blockIdx.x * 4 + w;
#pragma unroll
    for (int s = 0; s < 8; ++s) { sk[s][t] = BIGF; si[s][t] = 0x7fffffff; }
    float worst = BIGF; int wslot = 0;
    for (int i = 0; i < 62; ++i) {
        int e = lane + 64 * i;
        if (e < NCAND) {
            float key = ck[q * NCAND + e];
            if (key < worst) {
                sk[wslot][t] = key; si[wslot][t] = ci[q * NCAND + e];
                worst = sk[0][t]; wslot = 0;
#pragma unroll
                for (int s = 1; s < 8; ++s)
                    if (sk[s][t] > worst) { worst = sk[s][t]; wslot = s; }
            }
        }
    }
    for (int r = 0; r < 32; ++r) {
        float mk = sk[0][t]; int mi = si[0][t]; int ms = 0;
#pragma unroll
        for (int s = 1; s < 8; ++s) {
            float k2 = sk[s][t]; int i2 = si[s][t];
            if (k2 < mk || (k2 == mk && i2 < mi)) { mk = k2; mi = i2; ms = s; }
        }
        int ml = lane;
        for (int off = 32; off; off >>= 1) {
            float ok = __shfl_down(mk, off); int oi = __shfl_down(mi, off);
            int ol = __shfl_down(ml, off);   int os = __shfl_down(ms, off);
            if (ok < mk || (ok == mk && oi < mi)) { mk = ok; mi = oi; ml = ol; ms = os; }
        }
        mi = __shfl(mi, 0); ml = __shfl(ml, 0); ms = __shfl(ms, 0);
        if (lane == 0) cand32[q * 32 + r] = mi;
        if (lane == ml) { sk[ms][t] = BIGF; si[ms][t] = 0x7fffffff; }
    }
}

// ---------------- exact fp32 rerank of 32 cands -> top-16 + softmax ----------------
__global__ __launch_bounds__(256) void rerank(const float* __restrict__ Tm,
                                              const float* __restrict__ X,
                                              const int* __restrict__ cand32,
                                              int* __restrict__ post_idx,
                                              float* __restrict__ post_w) {
    __shared__ float Ts[256];
    __shared__ float d2s[32];
    __shared__ float l2sorted[16];
    __shared__ int   idxsorted[16];
    int q = blockIdx.x, t = threadIdx.x;
    Ts[t] = Tm[q * 256 + t];
    __syncthreads();
    int c = t >> 3, dl = t & 7;
    int idx = cand32[q * 32 + c];
    float s = 0.f;
    for (int i = 0; i < 32; ++i) {
        int d = dl + 8 * i;
        float df = Ts[d] - X[(size_t)idx * 256 + d];
        s += df * df;
    }
    s += __shfl_down(s, 4, 8); s += __shfl_down(s, 2, 8); s += __shfl_down(s, 1, 8);
    if (dl == 0) d2s[c] = s;
    __syncthreads();
    if (t < 64) {
        float key = (t < 32) ? d2s[t] : BIGF;
        int   myi = (t < 32) ? cand32[q * 32 + t] : 0x7fffffff;
        bool used = false;
        for (int r = 0; r < 16; ++r) {
            float mk = used ? BIGF : key; int mi = myi; int ml = t;
            for (int off = 32; off; off >>= 1) {
                float ok = __shfl_down(mk, off); int oi = __shfl_down(mi, off); int ol = __shfl_down(ml, off);
                if (ok < mk || (ok == mk && oi < mi)) { mk = ok; mi = oi; ml = ol; }
            }
            mk = __shfl(mk, 0); mi = __shfl(mi, 0); ml = __shfl(ml, 0);
            if (t == ml) used = true;
            if (t == 0) { l2sorted[r] = mk; idxsorted[r] = mi; }
        }
    }
    __syncthreads();
    if (t < 16) {
        float w = expf(-10.0f * (l2sorted[t] - l2sorted[0]));
        float sum = w;
        for (int off = 8; off; off >>= 1) sum += __shfl_xor(sum, off, 16);
        post_w[q * 16 + t] = w / sum;
        post_idx[q * 16 + t] = idxsorted[t];
    }
}

// ---------------- KL per sample (exact reference semantics) ----------------
__global__ __launch_bounds__(256) void kl_kernel(const int* __restrict__ q_indices,
                                                 const int* __restrict__ pre_indices,
                                                 const float* __restrict__ pre_weights,
                                                 const int* __restrict__ post_idx,
                                                 const float* __restrict__ post_w,
                                                 float* __restrict__ scal) {
    int b = threadIdx.x;
    int qi = q_indices[b];
    int pid[16]; float pw[16]; int sid[16]; float sw[16];
    for (int k = 0; k < 16; ++k) {
        pid[k] = pre_indices[qi * 16 + k];
        pw[k]  = pre_weights[qi * 16 + k];
        sid[k] = post_idx[b * 16 + k];
        sw[k]  = post_w[b * 16 + k];
    }
    float psum = 0.f, qsum = 0.f, kl = 0.f;
    for (int pass = 0; pass < 2; ++pass) {
        for (int i = 0; i < 32; ++i) {
            int c = (i < 16) ? pid[i] : sid[i - 16];
            bool first = true;
            for (int jj = 0; jj < i; ++jj) {
                int cj = (jj < 16) ? pid[jj] : sid[jj - 16];
                if (cj == c) { first = false; break; }
            }
            if (!first) continue;
            float p = 0.f, q = 0.f;
            for (int k2 = 0; k2 < 16; ++k2) {
                if (pid[k2] == c) p += pw[k2];
                if (sid[k2] == c) q += sw[k2];
            }
            p = fmaxf(p, 1e-8f); q = fmaxf(q, 1e-8f);
            if (pass == 0) { psum += p; qsum += q; }
            else {
                float pn = p / psum, qn = q / qsum;
                kl += pn * (logf(pn) - logf(qn));
            }
        }
    }
    atomicAdd(&scal[SC_KNN], kl * (1.0f / 256.0f));
}

// ---------------- final assembly ----------------
__global__ void assemble_kernel(const float* __restrict__ scal, float* __restrict__ out) {
    if (threadIdx.x == 0) {
        float ld = scal[SC_LD], lk = scal[SC_KNN], reg = scal[SC_REG];
        out[0] = ld + lk + 1e-4f * 0.5f * reg;
        out[1] = ld;
        out[2] = lk;
    }
}

extern "C" void kernel_launch(void* const* d_in, const int* in_sizes, int n_in,
                              void* d_out, int out_size, void* d_ws, size_t ws_size,
                              hipStream_t stream) {
    (void)in_sizes; (void)n_in; (void)out_size; (void)ws_size;
    const float* X           = (const float*)d_in[0];
    const float* W           = (const float*)d_in[1];
    const float* q_batch     = (const float*)d_in[2];
    const float* pre_weights = (const float*)d_in[3];
    const int*   q_indices   = (const int*)d_in[4];
    const int*   pre_indices = (const int*)d_in[5];
    float* out = (float*)d_out;
    float* ws  = (float*)d_ws;

    float*  scal     = ws + O_SCAL;
    ushort* Xb       = (ushort*)(ws + O_XB);
    ushort* Tb       = (ushort*)(ws + O_TB);
    float*  xsq      = ws + O_XSQ;
    float*  ck       = ws + O_CK;
    int*    ci       = (int*)(ws + O_CI);
    int*    cand32   = (int*)(ws + O_CAND);
    int*    post_idx = (int*)(ws + O_POSTI);
    float*  post_w   = ws + O_POSTW;

    zero_kernel<<<290, 256, 0, stream>>>(ws);
    reg_kernel<<<64, 256, 0, stream>>>(W, scal);
    statsconv<<<98, 256, 0, stream>>>(X, xsq, ws + O_MUSUM, Xb);
    covx_mfma<<<126, 256, 0, stream>>>(Xb, ws + O_COVXA);
    persist<<<NB, 256, 0, stream>>>(q_batch, W, ws);
    knn_mfma<<<dim3(782, 2), 256, 0, stream>>>(Xb, Tb, xsq, ck, ci);
    merge_kernel<<<64, 256, 0, stream>>>(ck, ci, cand32);
    rerank<<<256, 256, 0, stream>>>(ws + O_TM, X, cand32, post_idx, post_w);
    kl_kernel<<<1, 256, 0, stream>>>(q_indices, pre_indices, pre_weights, post_idx, post_w, scal);
    assemble_kernel<<<1, 64, 0, stream>>>(scal, out);
}